// Round 1
// baseline (74.259 us; speedup 1.0000x reference)
//
#include <hip/hip_runtime.h>

// EllipticalShapeLoss: one streaming pass computes exact integer raw moments
// M_pq = sum_{mask} y^p x^q (p+q<=4) per batch in int64; a tiny second kernel
// does the per-batch covariance/quartic algebra in double.

constexpr int BATCH = 32;
constexpr int H = 1024;
constexpr int W = 1024;
constexpr int NPIX = H * W;                       // 1048576
constexpr int NMOM = 15;
constexpr int RUN = 16;                           // pixels per run (one row segment)
constexpr int RUNS_PER_BATCH = NPIX / RUN;        // 65536
constexpr int TPB = 256;
constexpr int BLOCKS_PER_BATCH = 32;
constexpr int TPBATCH = TPB * BLOCKS_PER_BATCH;   // 8192 threads per batch
constexpr int RUNS_PER_THREAD = RUNS_PER_BATCH / TPBATCH;  // 8

// moment index -> (p,q):  0:(0,0) 1:(1,0) 2:(0,1) 3:(2,0) 4:(1,1) 5:(0,2)
// 6:(3,0) 7:(2,1) 8:(1,2) 9:(0,3) 10:(4,0) 11:(3,1) 12:(2,2) 13:(1,3) 14:(0,4)

__global__ __launch_bounds__(TPB) void esl_moments(
    const float* __restrict__ probs, unsigned long long* __restrict__ mom) {
  const int b = blockIdx.x / BLOCKS_PER_BATCH;
  const int blk = blockIdx.x % BLOCKS_PER_BATCH;
  const int tb = blk * TPB + threadIdx.x;          // thread index within batch
  const float* __restrict__ p0 = probs + (size_t)b * 2 * NPIX;
  const float* __restrict__ p1 = p0 + NPIX;

  double acc[NMOM];
#pragma unroll
  for (int i = 0; i < NMOM; ++i) acc[i] = 0.0;

  for (int k = 0; k < RUNS_PER_THREAD; ++k) {
    const int rid = k * TPBATCH + tb;              // run id in [0, 65536)
    const int off = rid * RUN;                     // pixel offset in batch plane
    const int y = rid >> 6;                        // 64 runs per row
    const int x0 = (rid & 63) << 4;                // run start column
    const float4* a4 = reinterpret_cast<const float4*>(p0 + off);
    const float4* b4 = reinterpret_cast<const float4*>(p1 + off);

    // local moments over u = x - x0 in [0,16); all fit u32 comfortably
    unsigned s0 = 0, s1 = 0, s2 = 0, s3 = 0, s4 = 0;
#pragma unroll
    for (int j = 0; j < 4; ++j) {
      const float4 av = a4[j];
      const float4 bv = b4[j];
      const float pa[4] = {av.x, av.y, av.z, av.w};
      const float pb[4] = {bv.x, bv.y, bv.z, bv.w};
#pragma unroll
      for (int t = 0; t < 4; ++t) {
        const unsigned u = (unsigned)(j * 4 + t);  // compile-time constant
        const bool m = pb[t] > pa[t];              // argmax==1 (ties -> class 0)
        s0 += m ? 1u : 0u;
        s1 += m ? u : 0u;
        s2 += m ? u * u : 0u;
        s3 += m ? u * u * u : 0u;
        s4 += m ? u * u * u * u : 0u;
      }
    }

    // binomial shift: T_q = sum_mask x^q over this run (exact in double)
    const double S0 = s0, S1 = s1, S2 = s2, S3 = s3, S4 = s4;
    const double X = (double)x0;
    const double X2 = X * X, X3 = X2 * X, X4 = X2 * X2;
    const double T0 = S0;
    const double T1 = X * S0 + S1;
    const double T2 = X2 * S0 + 2.0 * X * S1 + S2;
    const double T3 = X3 * S0 + 3.0 * X2 * S1 + 3.0 * X * S2 + S3;
    const double T4 = X4 * S0 + 4.0 * X3 * S1 + 6.0 * X2 * S2 + 4.0 * X * S3 + S4;
    const double Y = (double)y;
    const double Y2 = Y * Y, Y3 = Y2 * Y, Y4 = Y2 * Y2;
    acc[0] += T0;
    acc[1] += Y * T0;
    acc[2] += T1;
    acc[3] += Y2 * T0;
    acc[4] += Y * T1;
    acc[5] += T2;
    acc[6] += Y3 * T0;
    acc[7] += Y2 * T1;
    acc[8] += Y * T2;
    acc[9] += T3;
    acc[10] += Y4 * T0;
    acc[11] += Y3 * T1;
    acc[12] += Y2 * T2;
    acc[13] += Y * T3;
    acc[14] += T4;
  }

  // wave shuffle reduce, then per-block LDS reduce, then int64 atomics
  const int lane = threadIdx.x & 63;
  const int wid = threadIdx.x >> 6;
  __shared__ double smem[TPB / 64][NMOM];
#pragma unroll
  for (int i = 0; i < NMOM; ++i) {
    double v = acc[i];
    for (int o = 32; o > 0; o >>= 1) v += __shfl_down(v, o, 64);
    if (lane == 0) smem[wid][i] = v;
  }
  __syncthreads();
  if (threadIdx.x < NMOM) {
    double v = 0.0;
#pragma unroll
    for (int wv = 0; wv < TPB / 64; ++wv) v += smem[wv][threadIdx.x];
    // block partials are integer-valued (<= ~3.6e16; tiny double rounding is
    // deterministic); int64 atomic accumulation is exact & order-independent
    atomicAdd(&mom[b * 16 + threadIdx.x], (unsigned long long)v);
  }
}

__global__ void esl_finalize(const unsigned long long* __restrict__ mom,
                             float* __restrict__ out) {
  const int lane = threadIdx.x;   // one wave of 64
  double loss = 0.0, valid = 0.0;
  if (lane < BATCH) {
    double M[NMOM];
#pragma unroll
    for (int i = 0; i < NMOM; ++i) M[i] = (double)mom[lane * 16 + i];
    const double n = M[0];
    const double n_safe = fmax(n, 2.0);
    const double ay = M[1] / n_safe;                  // centroid y
    const double ax = M[2] / n_safe;                  // centroid x
    const double ay2 = ay * ay, ay3 = ay2 * ay, ay4 = ay2 * ay2;
    const double ax2 = ax * ax, ax3 = ax2 * ax, ax4 = ax2 * ax2;

    // centered 2nd moments
    const double C20 = M[3] - 2.0 * ay * M[1] + ay2 * n;
    const double C11 = M[4] - ay * M[2] - ax * M[1] + ay * ax * n;
    const double C02 = M[5] - 2.0 * ax * M[2] + ax2 * n;

    const double denom = fmax(n_safe - 1.0, 1.0);
    const double Syy = C20 / denom, Sxy = C11 / denom, Sxx = C02 / denom;
    const double a = Syy + 1e-6, d = Sxx + 1e-6, bb = Sxy;
    const double det = a * d - bb * bb;
    const double i00 = d / det, i11 = a / det, i01 = -bb / det;

    // centered 4th moments from raw moments
    const double C40 = M[10] - 4.0 * ay * M[6] + 6.0 * ay2 * M[3]
                     - 4.0 * ay3 * M[1] + ay4 * n;
    const double C31 = M[11] - ax * M[6] - 3.0 * ay * M[7] + 3.0 * ay * ax * M[3]
                     + 3.0 * ay2 * M[4] - 3.0 * ay2 * ax * M[1]
                     - ay3 * M[2] + ay3 * ax * n;
    const double C22 = M[12] - 2.0 * ax * M[7] + ax2 * M[3] - 2.0 * ay * M[8]
                     + 4.0 * ay * ax * M[4] - 2.0 * ay * ax2 * M[1]
                     + ay2 * M[5] - 2.0 * ay2 * ax * M[2] + ay2 * ax2 * n;
    const double C13 = M[13] - ay * M[9] - 3.0 * ax * M[8] + 3.0 * ax * ay * M[5]
                     + 3.0 * ax2 * M[4] - 3.0 * ax2 * ay * M[2]
                     - ax3 * M[1] + ax3 * ay * n;
    const double C04 = M[14] - 4.0 * ax * M[9] + 6.0 * ax2 * M[5]
                     - 4.0 * ax3 * M[2] + ax4 * n;

    // sum w*m and sum w*m^2 via moment contraction
    const double Swm  = i00 * C20 + 2.0 * i01 * C11 + i11 * C02;
    const double Swm2 = i00 * i00 * C40 + 4.0 * i00 * i01 * C31
                      + (2.0 * i00 * i11 + 4.0 * i01 * i01) * C22
                      + 4.0 * i01 * i11 * C13 + i11 * i11 * C04;
    const double num = Swm2 - 2.0 * Swm + n;          // sum w*(m-1)^2
    const double loss_obj = num / n_safe;

    if (n >= 10.0) { valid = 1.0; loss = loss_obj; }
  }
  for (int o = 32; o > 0; o >>= 1) {
    loss += __shfl_down(loss, o, 64);
    valid += __shfl_down(valid, o, 64);
  }
  if (lane == 0) out[0] = (float)((valid > 0.0) ? loss / fmax(valid, 1.0) : 0.0);
}

extern "C" void kernel_launch(void* const* d_in, const int* in_sizes, int n_in,
                              void* d_out, int out_size, void* d_ws, size_t ws_size,
                              hipStream_t stream) {
  const float* probs = (const float*)d_in[0];
  float* out = (float*)d_out;
  unsigned long long* mom = (unsigned long long*)d_ws;
  hipMemsetAsync(mom, 0, BATCH * 16 * sizeof(unsigned long long), stream);
  esl_moments<<<BATCH * BLOCKS_PER_BATCH, TPB, 0, stream>>>(probs, mom);
  esl_finalize<<<1, 64, 0, stream>>>(mom, out);
}

// Round 2
// 57.655 us; speedup vs baseline: 1.2880x; 1.2880x over previous
//
#include <hip/hip_runtime.h>

// EllipticalShapeLoss: streaming pass computes raw moments M_pq = sum_mask y^p x^q
// (p+q<=4) per batch. Row-per-wave lane-contiguous float4 loads; per-block double
// partials to d_ws (no memset, no atomics, deterministic); tiny finalize kernel.

constexpr int BATCH = 32;
constexpr int H = 1024;
constexpr int W = 1024;
constexpr int NPIX = H * W;
constexpr int NMOM = 15;
constexpr int TPB = 256;                           // 4 waves per block
constexpr int WAVES_PER_BLOCK = TPB / 64;
constexpr int BLOCKS_PER_BATCH = 32;
constexpr int WAVES_PER_BATCH = BLOCKS_PER_BATCH * WAVES_PER_BLOCK;  // 128
constexpr int ROWS_PER_WAVE = H / WAVES_PER_BATCH;                   // 8
constexpr int NBLOCKS = BATCH * BLOCKS_PER_BATCH;                    // 1024

// moment index -> (p,q):  0:(0,0) 1:(1,0) 2:(0,1) 3:(2,0) 4:(1,1) 5:(0,2)
// 6:(3,0) 7:(2,1) 8:(1,2) 9:(0,3) 10:(4,0) 11:(3,1) 12:(2,2) 13:(1,3) 14:(0,4)

__global__ __launch_bounds__(TPB) void esl_moments(
    const float* __restrict__ probs, double* __restrict__ partials) {
  const int b = blockIdx.x >> 5;                   // batch
  const int blk = blockIdx.x & 31;                 // block within batch
  const int lane = threadIdx.x & 63;
  const int wid = threadIdx.x >> 6;
  const int wave_idx = blk * WAVES_PER_BLOCK + wid;  // wave within batch [0,128)
  const int y0 = wave_idx * ROWS_PER_WAVE;

  const float* __restrict__ p0 = probs + (size_t)b * 2 * NPIX;
  const float* __restrict__ p1 = p0 + NPIX;

  // thread-constant x base and its powers (lane l owns x = 4l + 256j + t)
  const double X = (double)(4 * lane);
  const double X2 = X * X, X3 = X2 * X, X4 = X2 * X2;

  double acc[NMOM];
#pragma unroll
  for (int i = 0; i < NMOM; ++i) acc[i] = 0.0;

  for (int r = 0; r < ROWS_PER_WAVE; ++r) {
    const int y = y0 + r;
    const float4* __restrict__ r0 =
        reinterpret_cast<const float4*>(p0 + (size_t)y * W);
    const float4* __restrict__ r1 =
        reinterpret_cast<const float4*>(p1 + (size_t)y * W);

    // issue all 8 lane-contiguous 16B loads up front (1 KB per wave per instr)
    float4 av[4], bv[4];
#pragma unroll
    for (int j = 0; j < 4; ++j) av[j] = r0[j * 64 + lane];
#pragma unroll
    for (int j = 0; j < 4; ++j) bv[j] = r1[j * 64 + lane];

    // masked power sums over v = 256j + t (compile-time literals)
    unsigned s0 = 0, s1 = 0, s2 = 0;
    unsigned long long s3 = 0, s4 = 0;
#pragma unroll
    for (int j = 0; j < 4; ++j) {
      const float pa[4] = {av[j].x, av[j].y, av[j].z, av[j].w};
      const float pb[4] = {bv[j].x, bv[j].y, bv[j].z, bv[j].w};
#pragma unroll
      for (int t = 0; t < 4; ++t) {
        const unsigned long long v = (unsigned long long)(256 * j + t);
        const bool m = pb[t] > pa[t];              // argmax==FG (ties -> class 0)
        s0 += m ? 1u : 0u;
        s1 += m ? (unsigned)v : 0u;
        s2 += m ? (unsigned)(v * v) : 0u;
        s3 += m ? v * v * v : 0ull;
        s4 += m ? v * v * v * v : 0ull;
      }
    }

    // binomial shift by X: T_q = sum_mask x^q over this thread's row pixels
    const double S0 = s0, S1 = s1, S2 = s2, S3 = (double)s3, S4 = (double)s4;
    const double T0 = S0;
    const double T1 = X * S0 + S1;
    const double T2 = X2 * S0 + 2.0 * X * S1 + S2;
    const double T3 = X3 * S0 + 3.0 * X2 * S1 + 3.0 * X * S2 + S3;
    const double T4 = X4 * S0 + 4.0 * X3 * S1 + 6.0 * X2 * S2 + 4.0 * X * S3 + S4;
    const double Y = (double)y;
    const double Y2 = Y * Y, Y3 = Y2 * Y, Y4 = Y2 * Y2;
    acc[0] += T0;
    acc[1] += Y * T0;
    acc[2] += T1;
    acc[3] += Y2 * T0;
    acc[4] += Y * T1;
    acc[5] += T2;
    acc[6] += Y3 * T0;
    acc[7] += Y2 * T1;
    acc[8] += Y * T2;
    acc[9] += T3;
    acc[10] += Y4 * T0;
    acc[11] += Y3 * T1;
    acc[12] += Y2 * T2;
    acc[13] += Y * T3;
    acc[14] += T4;
  }

  // wave shuffle reduce -> LDS across 4 waves -> per-block partial (no atomics)
  __shared__ double smem[WAVES_PER_BLOCK][NMOM];
#pragma unroll
  for (int i = 0; i < NMOM; ++i) {
    double v = acc[i];
    for (int o = 32; o > 0; o >>= 1) v += __shfl_down(v, o, 64);
    if (lane == 0) smem[wid][i] = v;
  }
  __syncthreads();
  if (threadIdx.x < NMOM) {
    double v = 0.0;
#pragma unroll
    for (int wv = 0; wv < WAVES_PER_BLOCK; ++wv) v += smem[wv][threadIdx.x];
    partials[blockIdx.x * 16 + threadIdx.x] = v;
  }
}

__global__ __launch_bounds__(512) void esl_finalize(
    const double* __restrict__ partials, float* __restrict__ out) {
  __shared__ double M[BATCH][16];
  __shared__ double red[2];
  const int tid = threadIdx.x;
  const int b = tid >> 4;
  const int i = tid & 15;
  if (i < NMOM) {
    double v = 0.0;
#pragma unroll
    for (int k = 0; k < BLOCKS_PER_BATCH; ++k)
      v += partials[(b * BLOCKS_PER_BATCH + k) * 16 + i];
    M[b][i] = v;
  }
  __syncthreads();

  double loss = 0.0, valid = 0.0;
  if (tid < BATCH) {
    const double* m = M[tid];
    const double n = m[0];
    const double n_safe = fmax(n, 2.0);
    const double ay = m[1] / n_safe;
    const double ax = m[2] / n_safe;
    const double ay2 = ay * ay, ay3 = ay2 * ay, ay4 = ay2 * ay2;
    const double ax2 = ax * ax, ax3 = ax2 * ax, ax4 = ax2 * ax2;

    const double C20 = m[3] - 2.0 * ay * m[1] + ay2 * n;
    const double C11 = m[4] - ay * m[2] - ax * m[1] + ay * ax * n;
    const double C02 = m[5] - 2.0 * ax * m[2] + ax2 * n;

    const double denom = fmax(n_safe - 1.0, 1.0);
    const double Syy = C20 / denom, Sxy = C11 / denom, Sxx = C02 / denom;
    const double a = Syy + 1e-6, d = Sxx + 1e-6, bb = Sxy;
    const double det = a * d - bb * bb;
    const double i00 = d / det, i11 = a / det, i01 = -bb / det;

    const double C40 = m[10] - 4.0 * ay * m[6] + 6.0 * ay2 * m[3]
                     - 4.0 * ay3 * m[1] + ay4 * n;
    const double C31 = m[11] - ax * m[6] - 3.0 * ay * m[7] + 3.0 * ay * ax * m[3]
                     + 3.0 * ay2 * m[4] - 3.0 * ay2 * ax * m[1]
                     - ay3 * m[2] + ay3 * ax * n;
    const double C22 = m[12] - 2.0 * ax * m[7] + ax2 * m[3] - 2.0 * ay * m[8]
                     + 4.0 * ay * ax * m[4] - 2.0 * ay * ax2 * m[1]
                     + ay2 * m[5] - 2.0 * ay2 * ax * m[2] + ay2 * ax2 * n;
    const double C13 = m[13] - ay * m[9] - 3.0 * ax * m[8] + 3.0 * ax * ay * m[5]
                     + 3.0 * ax2 * m[4] - 3.0 * ax2 * ay * m[2]
                     - ax3 * m[1] + ax3 * ay * n;
    const double C04 = m[14] - 4.0 * ax * m[9] + 6.0 * ax2 * m[5]
                     - 4.0 * ax3 * m[2] + ax4 * n;

    const double Swm  = i00 * C20 + 2.0 * i01 * C11 + i11 * C02;
    const double Swm2 = i00 * i00 * C40 + 4.0 * i00 * i01 * C31
                      + (2.0 * i00 * i11 + 4.0 * i01 * i01) * C22
                      + 4.0 * i01 * i11 * C13 + i11 * i11 * C04;
    const double loss_obj = (Swm2 - 2.0 * Swm + n) / n_safe;

    if (n >= 10.0) { valid = 1.0; loss = loss_obj; }
  }
  if (tid < 64) {
    for (int o = 32; o > 0; o >>= 1) {
      loss += __shfl_down(loss, o, 64);
      valid += __shfl_down(valid, o, 64);
    }
    if (tid == 0) {
      red[0] = loss; red[1] = valid;
      out[0] = (float)((red[1] > 0.0) ? red[0] / fmax(red[1], 1.0) : 0.0);
    }
  }
}

extern "C" void kernel_launch(void* const* d_in, const int* in_sizes, int n_in,
                              void* d_out, int out_size, void* d_ws, size_t ws_size,
                              hipStream_t stream) {
  const float* probs = (const float*)d_in[0];
  float* out = (float*)d_out;
  double* partials = (double*)d_ws;                // 1024 * 16 * 8 B = 128 KB
  esl_moments<<<NBLOCKS, TPB, 0, stream>>>(probs, partials);
  esl_finalize<<<1, 512, 0, stream>>>(partials, out);
}

// Round 3
// 56.123 us; speedup vs baseline: 1.3231x; 1.0273x over previous
//
#include <hip/hip_runtime.h>

// EllipticalShapeLoss: streaming pass computes raw moments M_pq = sum_mask y^p x^q
// (p+q<=4) per batch. Row-per-wave lane-contiguous nontemporal float4 loads with a
// 2-row software pipeline; per-block double partials to d_ws (no memset, no
// atomics, deterministic); tiny finalize kernel does the covariance algebra.

constexpr int BATCH = 32;
constexpr int H = 1024;
constexpr int W = 1024;
constexpr int NPIX = H * W;
constexpr int NMOM = 15;
constexpr int TPB = 256;                           // 4 waves per block
constexpr int WAVES_PER_BLOCK = TPB / 64;
constexpr int BLOCKS_PER_BATCH = 64;
constexpr int WAVES_PER_BATCH = BLOCKS_PER_BATCH * WAVES_PER_BLOCK;  // 256
constexpr int ROWS_PER_WAVE = H / WAVES_PER_BATCH;                   // 4
constexpr int NBLOCKS = BATCH * BLOCKS_PER_BATCH;                    // 2048

typedef float f32x4 __attribute__((ext_vector_type(4)));

// moment index -> (p,q):  0:(0,0) 1:(1,0) 2:(0,1) 3:(2,0) 4:(1,1) 5:(0,2)
// 6:(3,0) 7:(2,1) 8:(1,2) 9:(0,3) 10:(4,0) 11:(3,1) 12:(2,2) 13:(1,3) 14:(0,4)

__device__ __forceinline__ void load_row(const f32x4* __restrict__ r0,
                                         const f32x4* __restrict__ r1,
                                         int lane, f32x4* a, f32x4* b) {
#pragma unroll
  for (int j = 0; j < 4; ++j) a[j] = __builtin_nontemporal_load(r0 + j * 64 + lane);
#pragma unroll
  for (int j = 0; j < 4; ++j) b[j] = __builtin_nontemporal_load(r1 + j * 64 + lane);
}

__device__ __forceinline__ void compute_row(const f32x4* a, const f32x4* b, int y,
                                            const double X, const double X2,
                                            const double X3, const double X4,
                                            double* acc) {
  // masked power sums over v = 256j + t (compile-time literals)
  unsigned s0 = 0, s1 = 0, s2 = 0;
  unsigned long long s3 = 0, s4 = 0;
#pragma unroll
  for (int j = 0; j < 4; ++j) {
#pragma unroll
    for (int t = 0; t < 4; ++t) {
      const unsigned long long v = (unsigned long long)(256 * j + t);
      const bool m = b[j][t] > a[j][t];            // argmax==FG (ties -> class 0)
      s0 += m ? 1u : 0u;
      s1 += m ? (unsigned)v : 0u;
      s2 += m ? (unsigned)(v * v) : 0u;
      s3 += m ? v * v * v : 0ull;
      s4 += m ? v * v * v * v : 0ull;
    }
  }
  // binomial shift by X: T_q = sum_mask x^q over this thread's row pixels
  const double S0 = s0, S1 = s1, S2 = s2, S3 = (double)s3, S4 = (double)s4;
  const double T0 = S0;
  const double T1 = X * S0 + S1;
  const double T2 = X2 * S0 + 2.0 * X * S1 + S2;
  const double T3 = X3 * S0 + 3.0 * X2 * S1 + 3.0 * X * S2 + S3;
  const double T4 = X4 * S0 + 4.0 * X3 * S1 + 6.0 * X2 * S2 + 4.0 * X * S3 + S4;
  const double Y = (double)y;
  const double Y2 = Y * Y, Y3 = Y2 * Y, Y4 = Y2 * Y2;
  acc[0] += T0;
  acc[1] += Y * T0;
  acc[2] += T1;
  acc[3] += Y2 * T0;
  acc[4] += Y * T1;
  acc[5] += T2;
  acc[6] += Y3 * T0;
  acc[7] += Y2 * T1;
  acc[8] += Y * T2;
  acc[9] += T3;
  acc[10] += Y4 * T0;
  acc[11] += Y3 * T1;
  acc[12] += Y2 * T2;
  acc[13] += Y * T3;
  acc[14] += T4;
}

__global__ __launch_bounds__(TPB) void esl_moments(
    const float* __restrict__ probs, double* __restrict__ partials) {
  const int b = blockIdx.x / BLOCKS_PER_BATCH;
  const int blk = blockIdx.x % BLOCKS_PER_BATCH;
  const int lane = threadIdx.x & 63;
  const int wid = threadIdx.x >> 6;
  const int wave_idx = blk * WAVES_PER_BLOCK + wid;  // wave within batch
  const int y0 = wave_idx * ROWS_PER_WAVE;

  const float* __restrict__ p0 = probs + (size_t)b * 2 * NPIX;
  const float* __restrict__ p1 = p0 + NPIX;

  const double X = (double)(4 * lane);
  const double X2 = X * X, X3 = X2 * X, X4 = X2 * X2;

  double acc[NMOM];
#pragma unroll
  for (int i = 0; i < NMOM; ++i) acc[i] = 0.0;

  // 2-row software pipeline: row r+1's 8 loads are in flight while computing row r
  f32x4 a0[4], b0[4], a1[4], b1[4];
  {
    const int y = y0;
    load_row(reinterpret_cast<const f32x4*>(p0 + (size_t)y * W),
             reinterpret_cast<const f32x4*>(p1 + (size_t)y * W), lane, a0, b0);
  }
#pragma unroll
  for (int r = 0; r < ROWS_PER_WAVE; r += 2) {
    if (r + 1 < ROWS_PER_WAVE) {
      const int y = y0 + r + 1;
      load_row(reinterpret_cast<const f32x4*>(p0 + (size_t)y * W),
               reinterpret_cast<const f32x4*>(p1 + (size_t)y * W), lane, a1, b1);
    }
    compute_row(a0, b0, y0 + r, X, X2, X3, X4, acc);
    if (r + 2 < ROWS_PER_WAVE) {
      const int y = y0 + r + 2;
      load_row(reinterpret_cast<const f32x4*>(p0 + (size_t)y * W),
               reinterpret_cast<const f32x4*>(p1 + (size_t)y * W), lane, a0, b0);
    }
    if (r + 1 < ROWS_PER_WAVE) compute_row(a1, b1, y0 + r + 1, X, X2, X3, X4, acc);
  }

  // wave shuffle reduce -> LDS across 4 waves -> per-block partial (no atomics)
  __shared__ double smem[WAVES_PER_BLOCK][NMOM];
#pragma unroll
  for (int i = 0; i < NMOM; ++i) {
    double v = acc[i];
    for (int o = 32; o > 0; o >>= 1) v += __shfl_down(v, o, 64);
    if (lane == 0) smem[wid][i] = v;
  }
  __syncthreads();
  if (threadIdx.x < NMOM) {
    double v = 0.0;
#pragma unroll
    for (int wv = 0; wv < WAVES_PER_BLOCK; ++wv) v += smem[wv][threadIdx.x];
    partials[blockIdx.x * 16 + threadIdx.x] = v;
  }
}

__global__ __launch_bounds__(512) void esl_finalize(
    const double* __restrict__ partials, float* __restrict__ out) {
  __shared__ double M[BATCH][16];
  __shared__ double red[2];
  const int tid = threadIdx.x;
  const int b = tid >> 4;
  const int i = tid & 15;
  if (i < NMOM) {
    double v = 0.0;
#pragma unroll
    for (int k = 0; k < BLOCKS_PER_BATCH; ++k)
      v += partials[(b * BLOCKS_PER_BATCH + k) * 16 + i];
    M[b][i] = v;
  }
  __syncthreads();

  double loss = 0.0, valid = 0.0;
  if (tid < BATCH) {
    const double* m = M[tid];
    const double n = m[0];
    const double n_safe = fmax(n, 2.0);
    const double ay = m[1] / n_safe;
    const double ax = m[2] / n_safe;
    const double ay2 = ay * ay, ay3 = ay2 * ay, ay4 = ay2 * ay2;
    const double ax2 = ax * ax, ax3 = ax2 * ax, ax4 = ax2 * ax2;

    const double C20 = m[3] - 2.0 * ay * m[1] + ay2 * n;
    const double C11 = m[4] - ay * m[2] - ax * m[1] + ay * ax * n;
    const double C02 = m[5] - 2.0 * ax * m[2] + ax2 * n;

    const double denom = fmax(n_safe - 1.0, 1.0);
    const double Syy = C20 / denom, Sxy = C11 / denom, Sxx = C02 / denom;
    const double a = Syy + 1e-6, d = Sxx + 1e-6, bb = Sxy;
    const double det = a * d - bb * bb;
    const double i00 = d / det, i11 = a / det, i01 = -bb / det;

    const double C40 = m[10] - 4.0 * ay * m[6] + 6.0 * ay2 * m[3]
                     - 4.0 * ay3 * m[1] + ay4 * n;
    const double C31 = m[11] - ax * m[6] - 3.0 * ay * m[7] + 3.0 * ay * ax * m[3]
                     + 3.0 * ay2 * m[4] - 3.0 * ay2 * ax * m[1]
                     - ay3 * m[2] + ay3 * ax * n;
    const double C22 = m[12] - 2.0 * ax * m[7] + ax2 * m[3] - 2.0 * ay * m[8]
                     + 4.0 * ay * ax * m[4] - 2.0 * ay * ax2 * m[1]
                     + ay2 * m[5] - 2.0 * ay2 * ax * m[2] + ay2 * ax2 * n;
    const double C13 = m[13] - ay * m[9] - 3.0 * ax * m[8] + 3.0 * ax * ay * m[5]
                     + 3.0 * ax2 * m[4] - 3.0 * ax2 * ay * m[2]
                     - ax3 * m[1] + ax3 * ay * n;
    const double C04 = m[14] - 4.0 * ax * m[9] + 6.0 * ax2 * m[5]
                     - 4.0 * ax3 * m[2] + ax4 * n;

    const double Swm  = i00 * C20 + 2.0 * i01 * C11 + i11 * C02;
    const double Swm2 = i00 * i00 * C40 + 4.0 * i00 * i01 * C31
                      + (2.0 * i00 * i11 + 4.0 * i01 * i01) * C22
                      + 4.0 * i01 * i11 * C13 + i11 * i11 * C04;
    const double loss_obj = (Swm2 - 2.0 * Swm + n) / n_safe;

    if (n >= 10.0) { valid = 1.0; loss = loss_obj; }
  }
  if (tid < 64) {
    for (int o = 32; o > 0; o >>= 1) {
      loss += __shfl_down(loss, o, 64);
      valid += __shfl_down(valid, o, 64);
    }
    if (tid == 0) {
      red[0] = loss; red[1] = valid;
      out[0] = (float)((red[1] > 0.0) ? red[0] / fmax(red[1], 1.0) : 0.0);
    }
  }
}

extern "C" void kernel_launch(void* const* d_in, const int* in_sizes, int n_in,
                              void* d_out, int out_size, void* d_ws, size_t ws_size,
                              hipStream_t stream) {
  const float* probs = (const float*)d_in[0];
  float* out = (float*)d_out;
  double* partials = (double*)d_ws;                // 2048 * 16 * 8 B = 256 KB
  esl_moments<<<NBLOCKS, TPB, 0, stream>>>(probs, partials);
  esl_finalize<<<1, 512, 0, stream>>>(partials, out);
}